// Round 15
// baseline (207.786 us; speedup 1.0000x reference)
//
#include <hip/hip_runtime.h>
#include <stdint.h>
#include <stddef.h>

// Problem: X=2048, Y=256, F=128, H=8, NF=32, O=H*NF=256. f32 I/O, mask int32.
//
// Round 15 = round 8 base + column-split GEMM done with every spill lesson:
//  - 1024 thr, 16 waves, 4 waves/SIMD. f32x4/f16x8 types ONLY (f32x16 spills).
//  - Convert: wave w -> rows [16w,16w+16): per-kk transient f32x8 load, leaky,
//    f16 cvt -> ah[4] (16 regs) -> af LDS tile (r10 layout). Logits from ah.
//  - GEMM: wave (rg=w>>1, cg=w&1) = rows [32rg,+32) x cols [128cg,+128);
//    acc[2][8] f32x4 = 64 AGPR; A from LDS 8KB + B 32KB per wave per x
//    -> block LDS 640 KB/x (r8: 1 MB/x).
//  - Epilogue STREAMED (r12 lesson): per-row-slot scalar stats -> snq exchange;
//    contraction recomputes rs/nm per slot, accumulates p[4][2] scalars.
//  - 3 barriers/x; hazards WAR-separated (af/coefT/snq/outp audited).

typedef __attribute__((ext_vector_type(8))) _Float16 f16x8;  // 4 VGPRs
typedef __attribute__((ext_vector_type(8))) float f32x8;
typedef __attribute__((ext_vector_type(4))) float f32x4;

#define XPB 8
#define NBLK 256

// dynamic LDS layout (bytes) — total 158816 < 163840
#define OFF_W1   0u        // 65536: W1 f16 fragments [(nt*4+kk)][l][8] (16x16 order)
#define OFF_W2   65536u    // 4096 : W2 f16 fragments [kk][l][8] (cols 8..15 = 0)
#define OFF_A    69632u    // 65536: A  f16 fragments [(tile*4+kk)][l][8], tile 0..15
#define OFF_COEF 135168u   // 8224 : float[8][257] logits -> coefs (head-major, padded)
#define OFF_OUTP 143392u   // 8192 : float[16][128] per-wave output partials
#define OFF_SNQ  151584u   // 4096 : float snqS[256][2], snqQ[256][2]
#define OFF_B1   155680u   // 1024 : float[256]
#define OFF_G    156704u   // 1024
#define OFF_BT   157728u   // 1024
#define OFF_B2   158752u   // 64   : float[16]
#define LDS_BYTES 158816u

__device__ __forceinline__ f32x4 mfma16(f16x8 a, f16x8 b, f32x4 c){
  return __builtin_amdgcn_mfma_f32_16x16x32_f16(a, b, c, 0, 0, 0);
}

__global__ __launch_bounds__(1024, 4) void attn_main(
    const float* __restrict__ xy, const int* __restrict__ mask,
    const float* __restrict__ W1g, const float* __restrict__ b1g,
    const float* __restrict__ gammag, const float* __restrict__ betag,
    const float* __restrict__ W2g, const float* __restrict__ b2g,
    float* __restrict__ out)
{
  extern __shared__ char smem[];
  const int tid = threadIdx.x;
  const int l  = tid & 63;
  const int w  = tid >> 6;     // wave 0..15
  const int rg = w >> 1;       // GEMM rows [32rg, 32rg+32)
  const int cg = w & 1;        // GEMM cols [128cg, 128cg+128)
  const int lg = l >> 4;       // lane group 0..3
  const int lc = l & 15;

  _Float16* w1f = (_Float16*)(smem + OFF_W1);
  _Float16* w2f = (_Float16*)(smem + OFF_W2);
  _Float16* af  = (_Float16*)(smem + OFF_A);
  float* coefT = (float*)(smem + OFF_COEF);           // [8][257]
  float* outp  = (float*)(smem + OFF_OUTP);           // [16][128]
  float* snqS  = (float*)(smem + OFF_SNQ);            // [256][2]
  float* snqQ  = (float*)(smem + OFF_SNQ + 2048u);    // [256][2]
  float* ldsB1 = (float*)(smem + OFF_B1);
  float* ldsG  = (float*)(smem + OFF_G);
  float* ldsBt = (float*)(smem + OFF_BT);
  float* ldsB2 = (float*)(smem + OFF_B2);

  if (tid < 256){
    ldsB1[tid] = b1g[tid];
    ldsG[tid]  = gammag[tid];
    ldsBt[tid] = betag[tid];
  }
  if (tid < 16) ldsB2[tid] = (tid < 8) ? b2g[tid] : 0.f;

  // ---- gather W1 (f32) -> f16 16x16 fragment order (r8-verified):
  //      idx=((nt*4+kk)*64+l)*8+j, value=W1[f][o], f=kk*32+(l>>4)*8+j, o=nt*16+(l&15)
  #pragma unroll
  for (int i = 0; i < 4; ++i){
    int base = i * 8192 + tid * 8;
    int bl  = (base >> 3) & 63;
    int bkk = (base >> 9) & 3;
    int bnt = base >> 11;
    int o   = bnt * 16 + (bl & 15);
    int f0  = bkk * 32 + ((bl >> 4) << 3);
    f16x8 v;
    #pragma unroll
    for (int j = 0; j < 8; ++j) v[j] = (_Float16)W1g[(size_t)(f0 + j) * 256 + o];
    *(f16x8*)(w1f + base) = v;
  }
  // ---- gather W2 -> f16 fragments (pad cols 8..15 with zero) ----
  if (tid < 256){
    int base = tid * 8;
    int bl  = (base >> 3) & 63;
    int bkk = base >> 9;
    int h   = bl & 15;
    int f0  = bkk * 32 + ((bl >> 4) << 3);
    f16x8 v;
    #pragma unroll
    for (int j = 0; j < 8; ++j)
      v[j] = (h < 8) ? (_Float16)W2g[(size_t)(f0 + j) * 8 + h] : (_Float16)0.f;
    *(f16x8*)(w2f + base) = v;
  }
  __syncthreads();   // gathers + params visible

  const int x0 = blockIdx.x * XPB;

  #pragma clang loop unroll(disable)
  for (int xi = 0; xi < XPB; ++xi){
    const int x = x0 + xi;

    // ---- convert: wave w -> rows [16w,16w+16); per-kk transient load ----
    f16x8 ah[4];
    #pragma unroll
    for (int kk = 0; kk < 4; ++kk){
      f32x8 v = *(const f32x8*)(xy + (((size_t)x * 256 + w * 16 + lc) << 7)
                                   + kk * 32 + (lg << 3));
      f16x8 vh;
      #pragma unroll
      for (int j = 0; j < 8; ++j){
        float f = fmaxf(v[j], 0.f) + 0.01f * fminf(v[j], 0.f);
        vh[j] = (_Float16)f;
      }
      ah[kk] = vh;
      *(f16x8*)(af + ((w * 4 + kk) * 64 + l) * 8) = vh;   // A tile w -> LDS
    }
    int mk[4];
    if (w < 8){
      #pragma unroll
      for (int k = 0; k < 4; ++k) mk[k] = mask[(x << 8) + (k << 6) + l];
    }

    // ---- logits for rows [16w,16w+16): 4 MFMA from regs; all waves busy ----
    {
      f32x4 la = {0.f,0.f,0.f,0.f};
      #pragma unroll
      for (int kk = 0; kk < 4; ++kk){
        f16x8 wb = *(const f16x8*)(w2f + (kk * 64 + l) * 8);
        la = mfma16(ah[kk], wb, la);
      }
      if (lc < 8){
        float b2v = ldsB2[lc];
        #pragma unroll
        for (int r = 0; r < 4; ++r){
          int row = (w << 4) + (lg << 2) + r;   // C/D: row=(l>>4)*4+r, col=l&15 (head)
          coefT[lc * 257 + row] = la[r] + b2v;
        }
      }
    }
    __syncthreads();   // B1: A fragments + all logits visible

    // ---- softmax over Y for head w (waves 0-7; mask-fill logits with 0);
    //      other waves proceed to GEMM -> softmax latency overlapped ----
    if (w < 8){
      float lgv[4];
      #pragma unroll
      for (int k = 0; k < 4; ++k){
        float v = coefT[w * 257 + (k << 6) + l];
        lgv[k] = mk[k] ? 0.f : v;
      }
      float mx = fmaxf(fmaxf(lgv[0], lgv[1]), fmaxf(lgv[2], lgv[3]));
      #pragma unroll
      for (int mm = 1; mm < 64; mm <<= 1) mx = fmaxf(mx, __shfl_xor(mx, mm));
      float e[4]; float sum = 0.f;
      #pragma unroll
      for (int k = 0; k < 4; ++k){ e[k] = __expf(lgv[k] - mx); sum += e[k]; }
      #pragma unroll
      for (int mm = 1; mm < 64; mm <<= 1) sum += __shfl_xor(sum, mm);
      float inv = 1.f / sum;
      #pragma unroll
      for (int k = 0; k < 4; ++k) coefT[w * 257 + (k << 6) + l] = e[k] * inv;
    }

    // ---- GEMM: acc[rt][nt], rows 32rg+16rt+4lg+r, col 128cg+16nt+lc;
    //      A from LDS tiles 2rg/2rg+1, each B fragment feeds 2 MFMAs ----
    f32x4 acc[2][8];
    #pragma unroll
    for (int rt = 0; rt < 2; ++rt)
      #pragma unroll
      for (int nt = 0; nt < 8; ++nt)
        acc[rt][nt] = (f32x4){0.f,0.f,0.f,0.f};

    #pragma unroll
    for (int kk = 0; kk < 4; ++kk){
      f16x8 a0 = *(const f16x8*)(af + (((2 * rg    ) * 4 + kk) * 64 + l) * 8);
      f16x8 a1 = *(const f16x8*)(af + (((2 * rg + 1) * 4 + kk) * 64 + l) * 8);
      #pragma unroll
      for (int nt = 0; nt < 8; ++nt){
        f16x8 b = *(const f16x8*)(w1f + (((cg * 8 + nt) * 4 + kk) * 64 + l) * 8);
        acc[0][nt] = mfma16(a0, b, acc[0][nt]);
        acc[1][nt] = mfma16(a1, b, acc[1][nt]);
      }
    }

    // ---- hid = acc + b1; STREAMED per-row-slot stats -> snq[row][cg] ----
    #pragma unroll
    for (int nt = 0; nt < 8; ++nt){
      float bv = ldsB1[cg * 128 + nt * 16 + lc];
      #pragma unroll
      for (int rt = 0; rt < 2; ++rt)
        #pragma unroll
        for (int r = 0; r < 4; ++r)
          acc[rt][nt][r] += bv;
    }
    #pragma unroll
    for (int rt = 0; rt < 2; ++rt){
      #pragma unroll
      for (int r = 0; r < 4; ++r){
        float s = 0.f, q = 0.f;
        #pragma unroll
        for (int nt = 0; nt < 8; ++nt){
          float v = acc[rt][nt][r];
          s += v;
          q = fmaf(v, v, q);
        }
        #pragma unroll
        for (int mm = 1; mm <= 8; mm <<= 1){
          s += __shfl_xor(s, mm);
          q += __shfl_xor(q, mm);
        }
        if (lc == 0){
          int row = rg * 32 + rt * 16 + (lg << 2) + r;
          snqS[row * 2 + cg] = s;
          snqQ[row * 2 + cg] = q;
        }
      }
    }
    __syncthreads();   // B2: stats partials + softmax coefs visible

    // ---- contraction, streamed: p[h0][t] over this wave's 32 rows ----
    float p[4][2];
    #pragma unroll
    for (int h0 = 0; h0 < 4; ++h0){ p[h0][0] = 0.f; p[h0][1] = 0.f; }
    #pragma unroll
    for (int rt = 0; rt < 2; ++rt){
      #pragma unroll
      for (int r = 0; r < 4; ++r){
        int row = rg * 32 + rt * 16 + (lg << 2) + r;
        float st = snqS[row * 2] + snqS[row * 2 + 1];
        float qt = snqQ[row * 2] + snqQ[row * 2 + 1];
        float m  = st * (1.f / 256.f);
        float var = qt * (1.f / 256.f) - m * m;
        float rs = rsqrtf(fmaxf(var, 0.f) + 1e-5f);
        float nm = -rs * m;
        #pragma unroll
        for (int h0 = 0; h0 < 4; ++h0){
          float c = coefT[(cg * 4 + h0) * 257 + row];
          float crs = c * rs, cnm = c * nm;
          p[h0][0] = fmaf(crs, acc[rt][2 * h0    ][r], p[h0][0] + cnm);
          p[h0][1] = fmaf(crs, acc[rt][2 * h0 + 1][r], p[h0][1] + cnm);
        }
      }
    }
    #pragma unroll
    for (int h0 = 0; h0 < 4; ++h0){
      #pragma unroll
      for (int t = 0; t < 2; ++t){
        float v = p[h0][t];
        v += __shfl_xor(v, 16);
        v += __shfl_xor(v, 32);
        if (lg == 0) outp[w * 128 + (h0 * 2 + t) * 16 + lc] = v;
      }
    }
    __syncthreads();   // B3: outp partials visible

    // ---- cross-rowgroup reduce, apply gamma/beta, f32 store ----
    if (tid < 256){
      int cgc = tid >> 7, ci = tid & 127;
      float S = 0.f;
      #pragma unroll
      for (int r8_ = 0; r8_ < 8; ++r8_) S += outp[(r8_ * 2 + cgc) * 128 + ci];
      out[((size_t)x << 8) + tid] = fmaf(ldsG[tid], S, ldsBt[tid]);
    }
  }
}

extern "C" void kernel_launch(void* const* d_in, const int* in_sizes, int n_in,
                              void* d_out, int out_size, void* d_ws, size_t ws_size,
                              hipStream_t stream){
  (void)in_sizes; (void)n_in; (void)out_size; (void)d_ws; (void)ws_size;
  const float* xy    = (const float*)d_in[0];
  const int*   mask  = (const int*)d_in[1];
  const float* W1    = (const float*)d_in[2];
  const float* b1    = (const float*)d_in[3];
  const float* gamma = (const float*)d_in[4];
  const float* beta  = (const float*)d_in[5];
  const float* W2    = (const float*)d_in[6];
  const float* b2    = (const float*)d_in[7];

  hipFuncSetAttribute((const void*)attn_main,
                      hipFuncAttributeMaxDynamicSharedMemorySize, (int)LDS_BYTES);
  attn_main<<<NBLK, 1024, LDS_BYTES, stream>>>(xy, mask, W1, b1, gamma, beta, W2, b2,
                                               (float*)d_out);
}

// Round 16
// 103.129 us; speedup vs baseline: 2.0148x; 2.0148x over previous
//
#include <hip/hip_runtime.h>
#include <stdint.h>
#include <stddef.h>

// Problem: X=2048, Y=256, F=128, H=8, NF=32, O=H*NF=256. f32 I/O, mask int32.
//
// Round 16 = EXACT round-8 resubmit (empirical best: 101.2 us).
// r9-r15 tested: column-split (reg dup), A-in-LDS + wide epilogue, 32x32x16
// (f32x16 alloc pathology), unroll clamps, streamed epilogues, dual-group
// pipeline -- ALL regressed via scratch spill or lost wave parallelism.
// r8 is the config that fits the 4-waves/SIMD budget (64 AGPR acc + <64 arch):
//  - 1024-thread block (16 waves), wave w owns rows [16w,16w+16) x all 256 cols
//    acc[16] f32x4 = 64 AGPR; ah[4] = 16 regs; transient araw.
//  - one x per iteration, XPB=8, grid 256 (1 block/CU)
//  - 3 barriers/iter; f16 single-pass MFMA; softmax overlapped under GEMM;
//    algebraic gamma/beta fold at final store.

typedef __attribute__((ext_vector_type(8))) _Float16 f16x8;  // 4 VGPRs
typedef __attribute__((ext_vector_type(8))) float f32x8;
typedef __attribute__((ext_vector_type(4))) float f32x4;

#define XPB 8
#define NBLK 256

// dynamic LDS layout (bytes)
#define OFF_W1   0u        // 65536: W1 f16 fragments [(nt*4+kk)][l][8]
#define OFF_W2   65536u    // 4096 : W2 f16 fragments [kk][l][8] (cols 8..15 = 0)
#define OFF_COEF 69632u    // 8224 : float[8][257] logits -> coefs (head-major, padded)
#define OFF_OUTP 77856u    // 16384: float[16][256] per-wave output partials
#define OFF_B1   94240u    // 1024 : float[256]
#define OFF_G    95264u    // 1024
#define OFF_BT   96288u    // 1024
#define OFF_B2   97312u    // 64   : float[16]
#define LDS_BYTES 97376u

__device__ __forceinline__ f32x4 mfma16(f16x8 a, f16x8 b, f32x4 c){
  return __builtin_amdgcn_mfma_f32_16x16x32_f16(a, b, c, 0, 0, 0);
}

__global__ __launch_bounds__(1024, 4) void attn_main(
    const float* __restrict__ xy, const int* __restrict__ mask,
    const float* __restrict__ W1g, const float* __restrict__ b1g,
    const float* __restrict__ gammag, const float* __restrict__ betag,
    const float* __restrict__ W2g, const float* __restrict__ b2g,
    float* __restrict__ out)
{
  extern __shared__ char smem[];
  const int tid = threadIdx.x;
  const int l  = tid & 63;
  const int w  = tid >> 6;     // wave 0..15; owns rows [16w, 16w+16)
  const int lg = l >> 4;       // lane group 0..3
  const int lc = l & 15;

  _Float16* w1f = (_Float16*)(smem + OFF_W1);
  _Float16* w2f = (_Float16*)(smem + OFF_W2);
  float* coefT = (float*)(smem + OFF_COEF);   // [8][257]
  float* outp  = (float*)(smem + OFF_OUTP);   // [16][256]
  float* ldsB1 = (float*)(smem + OFF_B1);
  float* ldsG  = (float*)(smem + OFF_G);
  float* ldsBt = (float*)(smem + OFF_BT);
  float* ldsB2 = (float*)(smem + OFF_B2);

  if (tid < 256){
    ldsB1[tid] = b1g[tid];
    ldsG[tid]  = gammag[tid];
    ldsBt[tid] = betag[tid];
  }
  if (tid < 16) ldsB2[tid] = (tid < 8) ? b2g[tid] : 0.f;

  // ---- gather W1 (f32) -> f16 fragment order (1024 threads, 4 rounds):
  //      idx=((nt*4+kk)*64+l)*8+j, value=W1[f][o], f=kk*32+(l>>4)*8+j, o=nt*16+(l&15)
  #pragma unroll
  for (int i = 0; i < 4; ++i){
    int base = i * 8192 + tid * 8;
    int bl  = (base >> 3) & 63;
    int bkk = (base >> 9) & 3;
    int bnt = base >> 11;
    int o   = bnt * 16 + (bl & 15);
    int f0  = bkk * 32 + ((bl >> 4) << 3);
    f16x8 v;
    #pragma unroll
    for (int j = 0; j < 8; ++j) v[j] = (_Float16)W1g[(size_t)(f0 + j) * 256 + o];
    *(f16x8*)(w1f + base) = v;
  }
  // ---- gather W2 -> f16 fragments (pad cols 8..15 with zero) ----
  if (tid < 256){
    int base = tid * 8;
    int bl  = (base >> 3) & 63;
    int bkk = base >> 9;
    int h   = bl & 15;
    int f0  = bkk * 32 + ((bl >> 4) << 3);
    f16x8 v;
    #pragma unroll
    for (int j = 0; j < 8; ++j)
      v[j] = (h < 8) ? (_Float16)W2g[(size_t)(f0 + j) * 8 + h] : (_Float16)0.f;
    *(f16x8*)(w2f + base) = v;
  }
  __syncthreads();   // gathers + params visible

  const int x0 = blockIdx.x * XPB;

  for (int xi = 0; xi < XPB; ++xi){
    const int x = x0 + xi;

    // ---- A rows for this wave (dies right after convert) + mask (waves 0-7) ----
    f32x8 araw[4];
    #pragma unroll
    for (int kk = 0; kk < 4; ++kk)
      araw[kk] = *(const f32x8*)(xy + (((size_t)x * 256 + w * 16 + lc) << 7)
                                    + kk * 32 + (lg << 3));
    int mk[4];
    if (w < 8){
      #pragma unroll
      for (int k = 0; k < 4; ++k) mk[k] = mask[(x << 8) + (k << 6) + l];
    }

    // ---- leaky_relu (f32-exact) + convert to f16 ----
    f16x8 ah[4];
    #pragma unroll
    for (int kk = 0; kk < 4; ++kk){
      f32x8 v = araw[kk];
      f16x8 vh;
      #pragma unroll
      for (int j = 0; j < 8; ++j){
        float f = fmaxf(v[j], 0.f) + 0.01f * fminf(v[j], 0.f);
        vh[j] = (_Float16)f;
      }
      ah[kk] = vh;
    }

    // ---- logits: lr @ W2 (padded to 16 cols), 4 MFMA ----
    {
      f32x4 la = {0.f,0.f,0.f,0.f};
      #pragma unroll
      for (int kk = 0; kk < 4; ++kk){
        f16x8 wb = *(const f16x8*)(w2f + (kk * 64 + l) * 8);
        la = mfma16(ah[kk], wb, la);
      }
      if (lc < 8){
        float b2v = ldsB2[lc];
        #pragma unroll
        for (int r = 0; r < 4; ++r){
          int row = (w << 4) + (lg << 2) + r;   // C/D: row=(l>>4)*4+r, col=l&15 (head)
          coefT[lc * 257 + row] = la[r] + b2v;
        }
      }
    }
    __syncthreads();   // B1: all logits visible

    // ---- softmax over Y for head w (waves 0-7; mask-fill logits with 0);
    //      waves 8-15 proceed straight to GEMM -> softmax latency overlapped ----
    if (w < 8){
      float lgv[4];
      #pragma unroll
      for (int k = 0; k < 4; ++k){
        float v = coefT[w * 257 + (k << 6) + l];
        lgv[k] = mk[k] ? 0.f : v;
      }
      float mx = fmaxf(fmaxf(lgv[0], lgv[1]), fmaxf(lgv[2], lgv[3]));
      #pragma unroll
      for (int mm = 1; mm < 64; mm <<= 1) mx = fmaxf(mx, __shfl_xor(mx, mm));
      float e[4]; float sum = 0.f;
      #pragma unroll
      for (int k = 0; k < 4; ++k){ e[k] = __expf(lgv[k] - mx); sum += e[k]; }
      #pragma unroll
      for (int mm = 1; mm < 64; mm <<= 1) sum += __shfl_xor(sum, mm);
      float inv = 1.f / sum;
      #pragma unroll
      for (int k = 0; k < 4; ++k) coefT[w * 257 + (k << 6) + l] = e[k] * inv;
    }

    // ---- main GEMM: acc[nt], rows w*16+lg*4+r, col nt*16+lc ----
    f32x4 acc[16];
    #pragma unroll
    for (int nt = 0; nt < 16; ++nt) acc[nt] = (f32x4){0.f,0.f,0.f,0.f};

    #pragma unroll
    for (int nt = 0; nt < 16; ++nt){
      #pragma unroll
      for (int kk = 0; kk < 4; ++kk){
        f16x8 b = *(const f16x8*)(w1f + ((nt * 4 + kk) * 64 + l) * 8);
        acc[nt] = mfma16(ah[kk], b, acc[nt]);
      }
    }

    // ---- hid = acc + b1; LN stats (butterfly over lc bits 1,2,4,8) ----
    float s[4] = {0.f,0.f,0.f,0.f}, q[4] = {0.f,0.f,0.f,0.f};
    #pragma unroll
    for (int nt = 0; nt < 16; ++nt){
      float bv = ldsB1[nt * 16 + lc];
      #pragma unroll
      for (int r = 0; r < 4; ++r){
        float v = acc[nt][r] + bv;
        acc[nt][r] = v;
        s[r] += v;
        q[r] = fmaf(v, v, q[r]);
      }
    }
    #pragma unroll
    for (int mm = 1; mm <= 8; mm <<= 1){
      #pragma unroll
      for (int r = 0; r < 4; ++r){
        s[r] += __shfl_xor(s[r], mm);
        q[r] += __shfl_xor(q[r], mm);
      }
    }
    float mu[4], rstd[4];
    #pragma unroll
    for (int r = 0; r < 4; ++r){
      float m = s[r] * (1.f / 256.f);
      float var = q[r] * (1.f / 256.f) - m * m;
      mu[r] = m;
      rstd[r] = rsqrtf(fmaxf(var, 0.f) + 1e-5f);
    }
    __syncthreads();   // B2: softmax coefs visible (hidden under GEMM+stats)

    // ---- contraction: partial[col] = sum_{rows of wave} c*rstd*(hid - mu) ----
    #pragma unroll
    for (int h = 0; h < 8; ++h){
      float c2[4];
      float Dl = 0.f;
      #pragma unroll
      for (int r = 0; r < 4; ++r){
        float c = coefT[h * 257 + (w << 4) + (lg << 2) + r];
        float v = c * rstd[r];
        c2[r] = v;
        Dl = fmaf(v, mu[r], Dl);
      }
      #pragma unroll
      for (int t = 0; t < 2; ++t){
        int nt = h * 2 + t;               // cols nt*16+lc belong to head nt>>1 == h
        float p = -Dl;
        #pragma unroll
        for (int r = 0; r < 4; ++r) p = fmaf(c2[r], acc[nt][r], p);
        p += __shfl_xor(p, 16);
        p += __shfl_xor(p, 32);
        if (lg == 0) outp[w * 256 + nt * 16 + lc] = p;
      }
    }
    __syncthreads();   // B3: outp partials visible

    // ---- cross-wave reduce (16 waves), apply gamma/beta, f32 store ----
    if (tid < 256){
      float S = 0.f;
      #pragma unroll
      for (int ww = 0; ww < 16; ++ww) S += outp[ww * 256 + tid];
      out[((size_t)x << 8) + tid] = fmaf(ldsG[tid], S, ldsBt[tid]);
    }
  }
}

extern "C" void kernel_launch(void* const* d_in, const int* in_sizes, int n_in,
                              void* d_out, int out_size, void* d_ws, size_t ws_size,
                              hipStream_t stream){
  (void)in_sizes; (void)n_in; (void)out_size; (void)d_ws; (void)ws_size;
  const float* xy    = (const float*)d_in[0];
  const int*   mask  = (const int*)d_in[1];
  const float* W1    = (const float*)d_in[2];
  const float* b1    = (const float*)d_in[3];
  const float* gamma = (const float*)d_in[4];
  const float* beta  = (const float*)d_in[5];
  const float* W2    = (const float*)d_in[6];
  const float* b2    = (const float*)d_in[7];

  hipFuncSetAttribute((const void*)attn_main,
                      hipFuncAttributeMaxDynamicSharedMemorySize, (int)LDS_BYTES);
  attn_main<<<NBLK, 1024, LDS_BYTES, stream>>>(xy, mask, W1, b1, gamma, beta, W2, b2,
                                               (float*)d_out);
}